// Round 1
// baseline (6981.417 us; speedup 1.0000x reference)
//
#include <hip/hip_runtime.h>
#include <math.h>

// Problem constants (fixed by the reference)
#define BB 32
#define HH 512
#define VV 32000
#define TT 64

// Workspace layout (float offsets)
#define OFF_H0A 0
#define OFF_H0B 16384
#define OFF_H1A 32768
#define OFF_H1B 49152
#define OFF_H1T 65536
#define OFF_C0  81920
#define OFF_C1  98304
#define OFF_AMAX 114688  // 32 x unsigned long long

__device__ __forceinline__ float sigmoidf_(float x) { return 1.0f / (1.0f + expf(-x)); }

// ---------------------------------------------------------------------------
// Init: zero states, seed token = START_INDEX (1) via amax key low32 = ~1
// ---------------------------------------------------------------------------
__global__ void k_init(float* __restrict__ ws) {
    int idx = blockIdx.x * 256 + threadIdx.x;   // 64 blocks x 256 = 16384
    ws[OFF_H0A + idx] = 0.0f;
    ws[OFF_H1A + idx] = 0.0f;
    ws[OFF_C0 + idx]  = 0.0f;
    ws[OFF_C1 + idx]  = 0.0f;
    if (idx < BB) {
        ((unsigned long long*)(ws + OFF_AMAX))[idx] = 0xFFFFFFFEull;  // tok = 0xFFFFFFFF - low32 = 1
    }
}

// ---------------------------------------------------------------------------
// LSTM cell kernel (both layers).
// MODE 0: x = [emb[tok] (512) | context (512) | h0_prev (512)], KTOT=1536, KIH=1024
// MODE 1: x = [h0_new (512) | h1_prev (512)],                   KTOT=1024, KIH=512
// Grid: 256 blocks (2 hidden units each) x 256 threads.
// Thread (ks in [0,8), b in [0,32)) accumulates 8 gate rows (4 gates x 2 hu)
// over its k-slice; LDS reduction; 64 threads do the c/h update.
// ---------------------------------------------------------------------------
template <int MODE, int KTOT, int KIH>
__global__ __launch_bounds__(256) void k_lstm(
    const float* __restrict__ Wih, const float* __restrict__ Whh,
    const float* __restrict__ bih, const float* __restrict__ bhh,
    const float* __restrict__ src0,   // MODE0: context   MODE1: h0_new
    const float* __restrict__ src1,   // MODE0: h0_prev   MODE1: h1_prev
    const float* __restrict__ emb,
    const unsigned long long* __restrict__ amax_in,
    float* __restrict__ hN_out,       // natural [b][hu]
    float* __restrict__ hT_out,       // MODE1 only: transposed [hu][b]
    float* __restrict__ c_st,         // in-place [b][hu]
    unsigned long long* amax_reset)   // MODE1 only
{
    __shared__ __align__(16) float xs[2][32][132];   // x chunk, [b][k], padded
    __shared__ __align__(16) float wck[2][8][128];   // weight chunk, [row][k]
    __shared__ float gred[8][8][32];                 // [ks][row][b]

    const int tid = threadIdx.x;
    const int hu0 = blockIdx.x * 2;

    // staging ids
    const int sb  = tid >> 3;   // batch 0..31
    const int skq = tid & 7;    // 16-float group 0..7
    // compute ids
    const int cks = tid >> 5;   // k-split 0..7
    const int cb  = tid & 31;   // batch

    int tok = 0;
    if constexpr (MODE == 0) {
        tok = (int)(0xFFFFFFFFu - (unsigned)(amax_in[sb] & 0xFFFFFFFFull));
    }

    constexpr int NCH = KTOT / 128;

    float acc[8];
#pragma unroll
    for (int r = 0; r < 8; ++r) acc[r] = 0.0f;

    auto stage = [&](int c, int bufi) {
        const int kc = c * 128;
        // x: 16 floats for batch sb
#pragma unroll
        for (int j4 = 0; j4 < 4; ++j4) {
            const int kl = skq * 16 + j4 * 4;
            const int kg = kc + kl;
            float4 v;
            if constexpr (MODE == 0) {
                if (kg < 512)       v = *(const float4*)(emb + (size_t)tok * 512 + kg);
                else if (kg < 1024) v = *(const float4*)(src0 + sb * 512 + (kg - 512));
                else                v = *(const float4*)(src1 + sb * 512 + (kg - 1024));
            } else {
                if (kg < 512)       v = *(const float4*)(src0 + sb * 512 + kg);
                else                v = *(const float4*)(src1 + sb * 512 + (kg - 512));
            }
            *(float4*)&xs[bufi][sb][kl] = v;
        }
        // w: row = tid>>5 (0..7 = g*2+huL), 4 floats at (tid&31)*4
        const int wr = tid >> 5;
        const int kl = (tid & 31) * 4;
        const int kg = kc + kl;
        const int g = wr >> 1, huL = wr & 1;
        const int rowg = g * 512 + hu0 + huL;
        float4 wv;
        if (kg < KIH) wv = *(const float4*)(Wih + (size_t)rowg * KIH + kg);
        else          wv = *(const float4*)(Whh + (size_t)rowg * 512 + (kg - KIH));
        *(float4*)&wck[bufi][wr][kl] = wv;
    };

    stage(0, 0);
    __syncthreads();
    for (int c = 0; c < NCH; ++c) {
        if (c + 1 < NCH) stage(c + 1, (c + 1) & 1);
        const int bufi = c & 1;
#pragma unroll
        for (int k4 = 0; k4 < 4; ++k4) {
            const int kl = cks * 16 + k4 * 4;
            const float4 xv = *(const float4*)&xs[bufi][cb][kl];
#pragma unroll
            for (int r = 0; r < 8; ++r) {
                const float4 wv = *(const float4*)&wck[bufi][r][kl];
                acc[r] += wv.x * xv.x + wv.y * xv.y + wv.z * xv.z + wv.w * xv.w;
            }
        }
        __syncthreads();
    }

#pragma unroll
    for (int r = 0; r < 8; ++r) gred[cks][r][cb] = acc[r];
    __syncthreads();

    if (tid < 64) {
        const int huL = tid >> 5, b = tid & 31;
        const int hu = hu0 + huL;
        float gate[4];
#pragma unroll
        for (int g = 0; g < 4; ++g) {
            float s = 0.0f;
#pragma unroll
            for (int ks = 0; ks < 8; ++ks) s += gred[ks][g * 2 + huL][b];
            gate[g] = s + bih[g * 512 + hu] + bhh[g * 512 + hu];
        }
        const float gi = sigmoidf_(gate[0]);
        const float gf = sigmoidf_(gate[1]);
        const float gg = tanhf(gate[2]);
        const float go = sigmoidf_(gate[3]);
        const float c_old = c_st[b * 512 + hu];
        const float cn = gf * c_old + gi * gg;
        const float hn = go * tanhf(cn);
        c_st[b * 512 + hu] = cn;
        hN_out[b * 512 + hu] = hn;
        if constexpr (MODE == 1) hT_out[hu * 32 + b] = hn;
    }
    if constexpr (MODE == 1) {
        if (tid >= 64 && tid < 96) amax_reset[tid - 64] = 0ull;
    }
}

// ---------------------------------------------------------------------------
// Output projection: logits[b][v] = h1 . Wout[v] + bout[v], written to
// d_out[b][t][v]; per-batch argmax accumulated into amax via 64-bit atomicMax.
// Grid: 500 blocks (64 rows each) x 256 threads (4-way k-split x 64 rows).
// x (h1T) addresses are wave-uniform -> scalar loads; W streams as float4.
// ---------------------------------------------------------------------------
__global__ __launch_bounds__(256, 2) void k_logits(
    const float* __restrict__ h1T,   // [512][32]
    const float* __restrict__ Wout, const float* __restrict__ bout,
    float* __restrict__ out,
    unsigned long long* __restrict__ amax, int t)
{
    __shared__ float red[4][64][33];
    __shared__ unsigned long long lmax[8][32];

    const int tid = threadIdx.x;
    const int ks = tid >> 6;     // 0..3 (wave-uniform)
    const int r  = tid & 63;
    const int row = blockIdx.x * 64 + r;

    float acc[32];
#pragma unroll
    for (int b = 0; b < 32; ++b) acc[b] = 0.0f;

    const float* wrow  = Wout + (size_t)row * 512 + ks * 128;
    const float* xbase = h1T + ks * 128 * 32;

    for (int k4 = 0; k4 < 32; ++k4) {
        const float4 w = *(const float4*)(wrow + k4 * 4);
        const float* x0 = xbase + (k4 * 4 + 0) * 32;
        const float* x1 = xbase + (k4 * 4 + 1) * 32;
        const float* x2 = xbase + (k4 * 4 + 2) * 32;
        const float* x3 = xbase + (k4 * 4 + 3) * 32;
#pragma unroll
        for (int b = 0; b < 32; ++b) {
            acc[b] += w.x * x0[b] + w.y * x1[b] + w.z * x2[b] + w.w * x3[b];
        }
    }

#pragma unroll
    for (int b = 0; b < 32; ++b) red[ks][r][b] = acc[b];
    __syncthreads();

    // phase 2: coalesced stores (lanes sweep consecutive vocab rows)
    {
        const int r2 = tid & 63, bq = tid >> 6;
        const int rowg = blockIdx.x * 64 + r2;
        const float bias = bout[rowg];
#pragma unroll
        for (int j = 0; j < 8; ++j) {
            const int b = bq * 8 + j;
            const float v = red[0][r2][b] + red[1][r2][b] + red[2][r2][b] + red[3][r2][b] + bias;
            out[((size_t)b * TT + t) * VV + rowg] = v;
        }
    }

    // phase 3: per-batch argmax candidates
    {
        const int b = tid & 31, rq = tid >> 5;
        unsigned long long best = 0ull;
#pragma unroll
        for (int j = 0; j < 8; ++j) {
            const int rr = rq * 8 + j;
            const int rowg = blockIdx.x * 64 + rr;
            const float v = red[0][rr][b] + red[1][rr][b] + red[2][rr][b] + red[3][rr][b] + bout[rowg];
            unsigned u = __float_as_uint(v);
            u = (u & 0x80000000u) ? ~u : (u | 0x80000000u);  // monotone float->uint
            const unsigned long long key =
                ((unsigned long long)u << 32) | (unsigned long long)(0xFFFFFFFFu - (unsigned)rowg);
            best = best > key ? best : key;
        }
        lmax[rq][b] = best;
    }
    __syncthreads();
    if (tid < 32) {
        unsigned long long bb = lmax[0][tid];
#pragma unroll
        for (int q = 1; q < 8; ++q) bb = bb > lmax[q][tid] ? bb : lmax[q][tid];
        const unsigned long long cur = amax[tid];
        if (bb > cur) atomicMax(&amax[tid], bb);  // skip-if-losing cuts contention
    }
}

// ---------------------------------------------------------------------------
// Final in-place log-softmax over each [b][t] row of d_out.
// ---------------------------------------------------------------------------
__global__ __launch_bounds__(256) void k_lsm(float* __restrict__ out) {
    float* p = out + (size_t)blockIdx.x * VV;
    const int tid = threadIdx.x;
    __shared__ float sred[4];
    __shared__ float sred2[4];

    float m = -1e30f;
    for (int i = tid * 4; i < VV; i += 1024) {
        const float4 v = *(const float4*)(p + i);
        m = fmaxf(m, fmaxf(fmaxf(v.x, v.y), fmaxf(v.z, v.w)));
    }
#pragma unroll
    for (int s = 32; s > 0; s >>= 1) m = fmaxf(m, __shfl_down(m, s, 64));
    if ((tid & 63) == 0) sred[tid >> 6] = m;
    __syncthreads();
    m = fmaxf(fmaxf(sred[0], sred[1]), fmaxf(sred[2], sred[3]));

    float s = 0.0f;
    for (int i = tid * 4; i < VV; i += 1024) {
        const float4 v = *(const float4*)(p + i);
        s += __expf(v.x - m) + __expf(v.y - m) + __expf(v.z - m) + __expf(v.w - m);
    }
#pragma unroll
    for (int o = 32; o > 0; o >>= 1) s += __shfl_down(s, o, 64);
    if ((tid & 63) == 0) sred2[tid >> 6] = s;
    __syncthreads();
    s = sred2[0] + sred2[1] + sred2[2] + sred2[3];
    const float lz = m + __logf(s);

    for (int i = tid * 4; i < VV; i += 1024) {
        float4 v = *(const float4*)(p + i);
        v.x -= lz; v.y -= lz; v.z -= lz; v.w -= lz;
        *(float4*)(p + i) = v;
    }
}

// ---------------------------------------------------------------------------
extern "C" void kernel_launch(void* const* d_in, const int* in_sizes, int n_in,
                              void* d_out, int out_size, void* d_ws, size_t ws_size,
                              hipStream_t stream) {
    const float* ctx  = (const float*)d_in[0];
    const float* emb  = (const float*)d_in[1];
    const float* Wih0 = (const float*)d_in[2];
    const float* Whh0 = (const float*)d_in[3];
    const float* bih0 = (const float*)d_in[4];
    const float* bhh0 = (const float*)d_in[5];
    const float* Wih1 = (const float*)d_in[6];
    const float* Whh1 = (const float*)d_in[7];
    const float* bih1 = (const float*)d_in[8];
    const float* bhh1 = (const float*)d_in[9];
    const float* Wout = (const float*)d_in[10];
    const float* bout = (const float*)d_in[11];

    float* out = (float*)d_out;
    float* ws  = (float*)d_ws;
    float* h0[2] = { ws + OFF_H0A, ws + OFF_H0B };
    float* h1[2] = { ws + OFF_H1A, ws + OFF_H1B };
    float* h1T = ws + OFF_H1T;
    float* c0  = ws + OFF_C0;
    float* c1  = ws + OFF_C1;
    unsigned long long* amax = (unsigned long long*)(ws + OFF_AMAX);

    k_init<<<64, 256, 0, stream>>>(ws);
    for (int t = 0; t < TT; ++t) {
        const int pp = t & 1, nn = pp ^ 1;
        k_lstm<0, 1536, 1024><<<256, 256, 0, stream>>>(
            Wih0, Whh0, bih0, bhh0, ctx, h0[pp], emb, amax,
            h0[nn], nullptr, c0, nullptr);
        k_lstm<1, 1024, 512><<<256, 256, 0, stream>>>(
            Wih1, Whh1, bih1, bhh1, h0[nn], h1[pp], emb, amax,
            h1[nn], h1T, c1, amax);
        k_logits<<<500, 256, 0, stream>>>(h1T, Wout, bout, out, amax, t);
    }
    k_lsm<<<BB * TT, 256, 0, stream>>>(out);
}

// Round 3
// 5521.816 us; speedup vs baseline: 1.2643x; 1.2643x over previous
//
#include <hip/hip_runtime.h>
#include <math.h>

#define BB 32
#define HH 512
#define VV 32000
#define TT 64

// Workspace layout (float offsets)
#define OFF_H0T  0        // 2 x [512][32]
#define OFF_H1T  32768    // 2 x [512][32]
#define OFF_C0   65536    // [hu][b] 512x32
#define OFF_C1   81920
#define OFF_PC0  98304    // [2048][32]  ctx-part of L0 gates + biases
#define OFF_AMAX 163840   // 32 x unsigned long long

__device__ __forceinline__ float sigmoidf_(float x) { return 1.0f / (1.0f + expf(-x)); }

__device__ __forceinline__ float dot4(const float4 wv, const float4 xv) {
    return wv.x * xv.x + wv.y * xv.y + wv.z * xv.z + wv.w * xv.w;
}
__device__ __forceinline__ void bcast_fma(float* A, const float4 wv,
                                          const float4 x0, const float4 x1,
                                          const float4 x2, const float4 x3) {
    A[0] += wv.x * x0.x + wv.y * x1.x + wv.z * x2.x + wv.w * x3.x;
    A[1] += wv.x * x0.y + wv.y * x1.y + wv.z * x2.y + wv.w * x3.y;
    A[2] += wv.x * x0.z + wv.y * x1.z + wv.z * x2.z + wv.w * x3.z;
    A[3] += wv.x * x0.w + wv.y * x1.w + wv.z * x2.w + wv.w * x3.w;
}

// ---------------------------------------------------------------------------
__global__ void k_init(float* __restrict__ ws) {
    int idx = blockIdx.x * 256 + threadIdx.x;   // 64 x 256 = 16384
    ws[OFF_H0T + idx] = 0.0f;   // h0T buffer 0
    ws[OFF_H1T + idx] = 0.0f;   // h1T buffer 0
    ws[OFF_C0 + idx]  = 0.0f;
    ws[OFF_C1 + idx]  = 0.0f;
    if (idx < BB) ((unsigned long long*)(ws + OFF_AMAX))[idx] = 0xFFFFFFFEull; // tok=1
}

// ---------------------------------------------------------------------------
// pc0[r][b] = sum_k Wih0[r][512+k]*ctx[b][k] + bih0[r] + bhh0[r]
// grid 128 blocks (4 hu each) x 256 threads: ks16 x bg4(B=8) x rg4(hu)
// ---------------------------------------------------------------------------
__global__ __launch_bounds__(256, 4) void k_pc0(
    const float* __restrict__ Wih0, const float* __restrict__ ctx,
    const float* __restrict__ bih0, const float* __restrict__ bhh0,
    float* __restrict__ pc0)
{
    __shared__ float red[16][16][32];
    const int tid = threadIdx.x;
    const int ks = tid >> 4, bg = (tid >> 2) & 3, rg = tid & 3;
    const int hu = blockIdx.x * 4 + rg;
    const int k0 = ks * 32, b0 = bg * 8;

    float acc[4][8];
#pragma unroll
    for (int g = 0; g < 4; ++g)
#pragma unroll
        for (int j = 0; j < 8; ++j) acc[g][j] = 0.0f;

    const float* wp[4];
#pragma unroll
    for (int g = 0; g < 4; ++g) wp[g] = Wih0 + (size_t)(g * 512 + hu) * 1024 + 512 + k0;

#pragma unroll 2
    for (int kk4 = 0; kk4 < 8; ++kk4) {
        const int kk = kk4 * 4;
        float4 w4[4];
#pragma unroll
        for (int g = 0; g < 4; ++g) w4[g] = *(const float4*)(wp[g] + kk);
#pragma unroll
        for (int j = 0; j < 8; ++j) {
            const float4 xe = *(const float4*)(ctx + (size_t)(b0 + j) * 512 + k0 + kk);
#pragma unroll
            for (int g = 0; g < 4; ++g) acc[g][j] += dot4(w4[g], xe);
        }
    }

#pragma unroll
    for (int g = 0; g < 4; ++g) {
        *(float4*)&red[ks][g * 4 + rg][b0]     = make_float4(acc[g][0], acc[g][1], acc[g][2], acc[g][3]);
        *(float4*)&red[ks][g * 4 + rg][b0 + 4] = make_float4(acc[g][4], acc[g][5], acc[g][6], acc[g][7]);
    }
    __syncthreads();
    if (tid < 128) {
        const int huL = (tid >> 5) & 3, b = tid & 31;
#pragma unroll
        for (int g = 0; g < 4; ++g) {
            float s = 0.0f;
#pragma unroll
            for (int k = 0; k < 16; ++k) s += red[k][g * 4 + huL][b];
            const int row = g * 512 + blockIdx.x * 4 + huL;
            pc0[(size_t)row * 32 + b] = s + bih0[row] + bhh0[row];
        }
    }
}

// ---------------------------------------------------------------------------
// LSTM layer. gates[r][b] = sum_kA Wa[r][kA]*xA[kA][b] + sum_kB Wb[r][kB]*xB[kB][b]
// MODE0: xA = emb[tok[b]] (gather, k-contig), xB = h0T_prev; + pc0
// MODE1: xA = h0T_new (bcast [k][b]),        xB = h1T_prev; + biases
// grid 256 blocks (2 hu) x 256 threads: ks16(K=64) x bg8(B=4) x rg2(hu)
// ---------------------------------------------------------------------------
template <int MODE>
__global__ __launch_bounds__(256, 4) void k_lstm(
    const float* __restrict__ Wa, const float* __restrict__ Wb,
    const float* __restrict__ xA, const float* __restrict__ xB,
    const float* __restrict__ emb,
    const unsigned long long* __restrict__ amax_in,
    const float* __restrict__ pc0,
    const float* __restrict__ bih, const float* __restrict__ bhh,
    float* __restrict__ hT_out, float* __restrict__ c_st,
    unsigned long long* __restrict__ amax_reset)
{
    constexpr int SA = (MODE == 0) ? 1024 : 512;   // Wa row stride
    __shared__ float red[16][8][32];

    const int tid = threadIdx.x;
    const int ks = tid >> 4, bg = (tid >> 1) & 7, rg = tid & 1;
    const int hu = blockIdx.x * 2 + rg;
    const int b0 = bg * 4;
    const bool partA = (ks < 8);           // wave-uniform (wave = 4 consecutive ks)
    const int k0 = (partA ? ks : ks - 8) * 64;

    float acc[4][4];
#pragma unroll
    for (int g = 0; g < 4; ++g)
#pragma unroll
        for (int j = 0; j < 4; ++j) acc[g][j] = 0.0f;

    const float* wp[4];
#pragma unroll
    for (int g = 0; g < 4; ++g)
        wp[g] = partA ? (Wa + (size_t)(g * 512 + hu) * SA + k0)
                      : (Wb + (size_t)(g * 512 + hu) * 512 + k0);

    const float* ep[4];
    if (MODE == 0 && partA) {
#pragma unroll
        for (int j = 0; j < 4; ++j) {
            const int tok = (int)(0xFFFFFFFFu - (unsigned)(amax_in[b0 + j] & 0xFFFFFFFFull));
            ep[j] = emb + (size_t)tok * 512 + k0;
        }
    }
    const float* xb = (partA ? xA : xB) + (size_t)k0 * 32 + b0;

#pragma unroll 2
    for (int kk4 = 0; kk4 < 16; ++kk4) {
        const int kk = kk4 * 4;
        float4 w4[4];
#pragma unroll
        for (int g = 0; g < 4; ++g) w4[g] = *(const float4*)(wp[g] + kk);
        if (MODE == 0 && partA) {
#pragma unroll
            for (int j = 0; j < 4; ++j) {
                const float4 xe = *(const float4*)(ep[j] + kk);
#pragma unroll
                for (int g = 0; g < 4; ++g) acc[g][j] += dot4(w4[g], xe);
            }
        } else {
            const float4 x0 = *(const float4*)(xb + (size_t)(kk + 0) * 32);
            const float4 x1 = *(const float4*)(xb + (size_t)(kk + 1) * 32);
            const float4 x2 = *(const float4*)(xb + (size_t)(kk + 2) * 32);
            const float4 x3 = *(const float4*)(xb + (size_t)(kk + 3) * 32);
#pragma unroll
            for (int g = 0; g < 4; ++g) bcast_fma(acc[g], w4[g], x0, x1, x2, x3);
        }
    }

#pragma unroll
    for (int g = 0; g < 4; ++g)
        *(float4*)&red[ks][g * 2 + rg][b0] = make_float4(acc[g][0], acc[g][1], acc[g][2], acc[g][3]);
    __syncthreads();

    if (tid < 64) {
        const int huL = tid >> 5, b = tid & 31;
        const int hu2 = blockIdx.x * 2 + huL;
        float gate[4];
#pragma unroll
        for (int g = 0; g < 4; ++g) {
            float s = 0.0f;
#pragma unroll
            for (int k = 0; k < 16; ++k) s += red[k][g * 2 + huL][b];
            const int row = g * 512 + hu2;
            if (MODE == 0) s += pc0[(size_t)row * 32 + b];
            else           s += bih[row] + bhh[row];
            gate[g] = s;
        }
        const float gi = sigmoidf_(gate[0]);
        const float gf = sigmoidf_(gate[1]);
        const float gg = tanhf(gate[2]);
        const float go = sigmoidf_(gate[3]);
        const int ci = hu2 * 32 + b;
        const float cn = gf * c_st[ci] + gi * gg;
        c_st[ci] = cn;
        hT_out[ci] = go * tanhf(cn);
    }
    if (MODE == 1) {
        if (tid >= 64 && tid < 96) amax_reset[tid - 64] = 0ull;
    }
}

// ---------------------------------------------------------------------------
// logits[row][b] = h1 . Wout[row] + bout[row]; write out[b][t][row]; argmax.
// grid 1000 blocks (32 rows) x 256 threads: ks8(K=64) x bg4(B=8) x rg8(R=4)
// ---------------------------------------------------------------------------
__global__ __launch_bounds__(256, 4) void k_logits(
    const float* __restrict__ h1T, const float* __restrict__ Wout,
    const float* __restrict__ bout, float* __restrict__ out,
    unsigned long long* __restrict__ amax, int t)
{
    __shared__ float red[8][32][36];
    __shared__ unsigned long long lmax[8][32];

    const int tid = threadIdx.x;
    const int rg = tid & 7, bg = (tid >> 3) & 3, ks = tid >> 5;
    const int row0 = blockIdx.x * 32 + rg * 4;
    const int b0 = bg * 8, k0 = ks * 64;

    float acc[4][8];
#pragma unroll
    for (int i = 0; i < 4; ++i)
#pragma unroll
        for (int j = 0; j < 8; ++j) acc[i][j] = 0.0f;

    const float* wp[4];
#pragma unroll
    for (int i = 0; i < 4; ++i) wp[i] = Wout + (size_t)(row0 + i) * 512 + k0;
    const float* xb = h1T + (size_t)k0 * 32 + b0;

#pragma unroll 2
    for (int kk4 = 0; kk4 < 16; ++kk4) {
        const int kk = kk4 * 4;
        const float4 x00 = *(const float4*)(xb + (size_t)(kk + 0) * 32);
        const float4 x01 = *(const float4*)(xb + (size_t)(kk + 0) * 32 + 4);
        const float4 x10 = *(const float4*)(xb + (size_t)(kk + 1) * 32);
        const float4 x11 = *(const float4*)(xb + (size_t)(kk + 1) * 32 + 4);
        const float4 x20 = *(const float4*)(xb + (size_t)(kk + 2) * 32);
        const float4 x21 = *(const float4*)(xb + (size_t)(kk + 2) * 32 + 4);
        const float4 x30 = *(const float4*)(xb + (size_t)(kk + 3) * 32);
        const float4 x31 = *(const float4*)(xb + (size_t)(kk + 3) * 32 + 4);
#pragma unroll
        for (int i = 0; i < 4; ++i) {
            const float4 w = *(const float4*)(wp[i] + kk);
            bcast_fma(&acc[i][0], w, x00, x10, x20, x30);
            bcast_fma(&acc[i][4], w, x01, x11, x21, x31);
        }
    }

#pragma unroll
    for (int i = 0; i < 4; ++i) {
        *(float4*)&red[ks][rg * 4 + i][b0]     = make_float4(acc[i][0], acc[i][1], acc[i][2], acc[i][3]);
        *(float4*)&red[ks][rg * 4 + i][b0 + 4] = make_float4(acc[i][4], acc[i][5], acc[i][6], acc[i][7]);
    }
    __syncthreads();

    // (a) coalesced stores
    {
        const int r2 = tid & 31, bq = tid >> 5;
        const int row = blockIdx.x * 32 + r2;
        const float bias = bout[row];
#pragma unroll
        for (int j = 0; j < 4; ++j) {
            const int b = bq * 4 + j;
            float v = bias;
#pragma unroll
            for (int k = 0; k < 8; ++k) v += red[k][r2][b];
            out[((size_t)b * TT + t) * VV + row] = v;
        }
    }
    // (b) per-batch argmax candidates
    {
        const int b = tid & 31, rq = tid >> 5;
        unsigned long long best = 0ull;
#pragma unroll
        for (int i = 0; i < 4; ++i) {
            const int rr = rq * 4 + i;
            const int row = blockIdx.x * 32 + rr;
            float v = bout[row];
#pragma unroll
            for (int k = 0; k < 8; ++k) v += red[k][rr][b];
            unsigned u = __float_as_uint(v);
            u = (u & 0x80000000u) ? ~u : (u | 0x80000000u);
            const unsigned long long key =
                ((unsigned long long)u << 32) | (unsigned long long)(0xFFFFFFFFu - (unsigned)row);
            best = best > key ? best : key;
        }
        lmax[rq][b] = best;
    }
    __syncthreads();
    if (tid < 32) {
        unsigned long long bb = lmax[0][tid];
#pragma unroll
        for (int q = 1; q < 8; ++q) bb = bb > lmax[q][tid] ? bb : lmax[q][tid];
        if (bb > amax[tid]) atomicMax(&amax[tid], bb);
    }
}

// ---------------------------------------------------------------------------
// log-softmax, fused online max+sum (2 sweeps instead of 3)
// ---------------------------------------------------------------------------
__global__ __launch_bounds__(256) void k_lsm(float* __restrict__ out) {
    float* p = out + (size_t)blockIdx.x * VV;
    const int tid = threadIdx.x;
    __shared__ float sm[4], ss[4];

    float m = -1e30f, s = 0.0f;
    for (int i = tid * 4; i < VV; i += 1024) {
        const float4 v = *(const float4*)(p + i);
        const float cm = fmaxf(fmaxf(v.x, v.y), fmaxf(v.z, v.w));
        const float nm = fmaxf(m, cm);
        s = s * __expf(m - nm) + __expf(v.x - nm) + __expf(v.y - nm)
                               + __expf(v.z - nm) + __expf(v.w - nm);
        m = nm;
    }
#pragma unroll
    for (int off = 32; off > 0; off >>= 1) {
        const float om = __shfl_down(m, off, 64);
        const float os = __shfl_down(s, off, 64);
        const float nm = fmaxf(m, om);
        s = s * __expf(m - nm) + os * __expf(om - nm);
        m = nm;
    }
    if ((tid & 63) == 0) { sm[tid >> 6] = m; ss[tid >> 6] = s; }
    __syncthreads();
    float M = sm[0], S = ss[0];
#pragma unroll
    for (int w = 1; w < 4; ++w) {
        const float nm = fmaxf(M, sm[w]);
        S = S * __expf(M - nm) + ss[w] * __expf(sm[w] - nm);
        M = nm;
    }
    const float lz = M + __logf(S);
    for (int i = tid * 4; i < VV; i += 1024) {
        float4 v = *(const float4*)(p + i);
        v.x -= lz; v.y -= lz; v.z -= lz; v.w -= lz;
        *(float4*)(p + i) = v;
    }
}

// ---------------------------------------------------------------------------
extern "C" void kernel_launch(void* const* d_in, const int* in_sizes, int n_in,
                              void* d_out, int out_size, void* d_ws, size_t ws_size,
                              hipStream_t stream) {
    const float* ctx  = (const float*)d_in[0];
    const float* emb  = (const float*)d_in[1];
    const float* Wih0 = (const float*)d_in[2];
    const float* Whh0 = (const float*)d_in[3];
    const float* bih0 = (const float*)d_in[4];
    const float* bhh0 = (const float*)d_in[5];
    const float* Wih1 = (const float*)d_in[6];
    const float* Whh1 = (const float*)d_in[7];
    const float* bih1 = (const float*)d_in[8];
    const float* bhh1 = (const float*)d_in[9];
    const float* Wout = (const float*)d_in[10];
    const float* bout = (const float*)d_in[11];

    float* out = (float*)d_out;
    float* ws  = (float*)d_ws;
    float* h0T[2] = { ws + OFF_H0T, ws + OFF_H0T + 16384 };
    float* h1T[2] = { ws + OFF_H1T, ws + OFF_H1T + 16384 };
    float* c0  = ws + OFF_C0;
    float* c1  = ws + OFF_C1;
    float* pc0 = ws + OFF_PC0;
    unsigned long long* amax = (unsigned long long*)(ws + OFF_AMAX);

    k_init<<<64, 256, 0, stream>>>(ws);
    k_pc0<<<128, 256, 0, stream>>>(Wih0, ctx, bih0, bhh0, pc0);

    for (int t = 0; t < TT; ++t) {
        const int pp = t & 1, nn = pp ^ 1;
        k_lstm<0><<<256, 256, 0, stream>>>(
            Wih0, Whh0, nullptr, h0T[pp], emb, amax, pc0, nullptr, nullptr,
            h0T[nn], c0, nullptr);
        k_lstm<1><<<256, 256, 0, stream>>>(
            Wih1, Whh1, h0T[nn], h1T[pp], emb, nullptr, nullptr, bih1, bhh1,
            h1T[nn], c1, amax);
        k_logits<<<1000, 256, 0, stream>>>(h1T[nn], Wout, bout, out, amax, t);
    }
    k_lsm<<<BB * TT, 256, 0, stream>>>(out);
}